// Round 1
// baseline (2305.879 us; speedup 1.0000x reference)
//
#include <hip/hip_runtime.h>
#include <math.h>

#define B_   2
#define T_   2048
#define C_   1024
#define H_   16
#define D_   64
#define NCH  32
#define RD   32
#define TOPB 8

// ---------------------------------------------------------------------------
// Tiled fp32 GEMM: out = A[M,K] @ Bm[K,N] + bias[N]
// MODE 0: plain row-major write to out[M,N]
// MODE 1: qkv scatter: col -> (which, h, d), row -> (b, t); write [B,H,T,D]
// 128x128 tile, BK=8, 256 threads, 8x8 per thread.
// ---------------------------------------------------------------------------
template <int MODE>
__global__ __launch_bounds__(256) void gemm128(
    const float* __restrict__ A, const float* __restrict__ Bm,
    const float* __restrict__ bias, float* __restrict__ out,
    int M, int N, int K,
    float* __restrict__ qp, float* __restrict__ kp, float* __restrict__ vp)
{
    __shared__ float As[8][128];
    __shared__ float Bs[8][128];

    const int tid = threadIdx.x;
    const int n0 = blockIdx.x * 128;
    const int m0 = blockIdx.y * 128;
    const int tx = tid & 15;       // col group
    const int ty = tid >> 4;       // row group

    const int ar = tid >> 1;           // A row within tile (0..127)
    const int ak = (tid & 1) * 4;      // A col within tile (0 or 4)
    const int bk = tid >> 5;           // B row within tile (0..7)
    const int bn = (tid & 31) * 4;     // B col within tile

    float acc[8][8];
#pragma unroll
    for (int i = 0; i < 8; i++)
#pragma unroll
        for (int j = 0; j < 8; j++) acc[i][j] = 0.f;

    for (int k0 = 0; k0 < K; k0 += 8) {
        float4 av = *(const float4*)&A[(size_t)(m0 + ar) * K + k0 + ak];
        float4 bv = *(const float4*)&Bm[(size_t)(k0 + bk) * N + n0 + bn];
        __syncthreads();
        As[ak + 0][ar] = av.x;
        As[ak + 1][ar] = av.y;
        As[ak + 2][ar] = av.z;
        As[ak + 3][ar] = av.w;
        *(float4*)&Bs[bk][bn] = bv;
        __syncthreads();
#pragma unroll
        for (int kk = 0; kk < 8; kk++) {
            float a[8], b[8];
            *(float4*)&a[0] = *(const float4*)&As[kk][ty * 8];
            *(float4*)&a[4] = *(const float4*)&As[kk][ty * 8 + 4];
            *(float4*)&b[0] = *(const float4*)&Bs[kk][tx * 8];
            *(float4*)&b[4] = *(const float4*)&Bs[kk][tx * 8 + 4];
#pragma unroll
            for (int i = 0; i < 8; i++)
#pragma unroll
                for (int j = 0; j < 8; j++) acc[i][j] += a[i] * b[j];
        }
    }

#pragma unroll
    for (int i = 0; i < 8; i++) {
        const int row = m0 + ty * 8 + i;
#pragma unroll
        for (int j = 0; j < 8; j++) {
            const int col = n0 + tx * 8 + j;
            const float vl = acc[i][j] + bias[col];
            if (MODE == 0) {
                out[(size_t)row * N + col] = vl;
            } else {
                const int which = col >> 10;     // 0=q 1=k 2=v
                const int c  = col & 1023;
                const int hh = c >> 6;
                const int dd = c & 63;
                const int bb = row >> 11;        // / T_
                const int tt = row & 2047;       // % T_
                float* dst = (which == 0) ? qp : (which == 1) ? kp : vp;
                dst[(((size_t)bb * H_ + hh) * T_ + tt) * D_ + dd] = vl;
            }
        }
    }
}

// ---------------------------------------------------------------------------
// chunk means: x[B,T,C] -> cm[B,NCH,C] (mean over CHUNK=64 rows)
// ---------------------------------------------------------------------------
__global__ void chunk_mean_kernel(const float* __restrict__ x, float* __restrict__ cm)
{
    const int bc = blockIdx.x;        // b*NCH + n
    const int b = bc >> 5, n = bc & 31;
    const float* xp = x + ((size_t)b * T_ + n * 64) * C_;
    for (int c = threadIdx.x; c < C_; c += blockDim.x) {
        float s = 0.f;
        for (int i = 0; i < 64; i++) s += xp[(size_t)i * C_ + c];
        cm[(size_t)bc * C_ + c] = s * (1.0f / 64.0f);
    }
}

// ---------------------------------------------------------------------------
// rowgemm32: dst[row][lane] = A[row,0:1024] @ W[1024,32] + bias[32]
// optional l2-normalize over the 32 cols. 8 rows per 256-thread block.
// ---------------------------------------------------------------------------
__global__ void rowgemm32(const float* __restrict__ A, const float* __restrict__ W,
                          const float* __restrict__ bias, float* __restrict__ dst,
                          int M, int normalize)
{
    const int row  = blockIdx.x * 8 + (threadIdx.x >> 5);
    const int lane = threadIdx.x & 31;
    if (row >= M) return;
    const float* a = A + (size_t)row * C_;
    float acc = 0.f;
    for (int k = 0; k < C_; k += 4) {
        float4 a4 = *(const float4*)&a[k];
        acc += a4.x * W[(k + 0) * RD + lane];
        acc += a4.y * W[(k + 1) * RD + lane];
        acc += a4.z * W[(k + 2) * RD + lane];
        acc += a4.w * W[(k + 3) * RD + lane];
    }
    acc += bias[lane];
    if (normalize) {
        float ss = acc * acc;
#pragma unroll
        for (int off = 16; off >= 1; off >>= 1) ss += __shfl_xor(ss, off, 32);
        acc = acc / fmaxf(sqrtf(ss), 1e-12f);
    }
    dst[(size_t)row * RD + lane] = acc;
}

// l2 normalize rows of src[M,32] -> dst
__global__ void l2norm_rows(const float* __restrict__ src, float* __restrict__ dst, int M)
{
    const int row  = blockIdx.x * 8 + (threadIdx.x >> 5);
    const int lane = threadIdx.x & 31;
    if (row >= M) return;
    float v = src[(size_t)row * RD + lane];
    float ss = v * v;
#pragma unroll
    for (int off = 16; off >= 1; off >>= 1) ss += __shfl_xor(ss, off, 32);
    dst[(size_t)row * RD + lane] = v / fmaxf(sqrtf(ss), 1e-12f);
}

// ---------------------------------------------------------------------------
// routing scores + top-8 (replicates lax.top_k tie-breaking: lower index wins)
// ---------------------------------------------------------------------------
__global__ void scores_topk(const float* __restrict__ qrt, const float* __restrict__ ren,
                            float* __restrict__ sc_out, float* __restrict__ idx_out)
{
    const int row = blockIdx.x * blockDim.x + threadIdx.x;   // 0 .. B*T-1
    if (row >= B_ * T_) return;
    const int b = row / T_;
    float q[RD];
#pragma unroll
    for (int i = 0; i < RD; i++) q[i] = qrt[(size_t)row * RD + i];
    const float* rb = ren + (size_t)b * NCH * RD;
    float s[NCH];
#pragma unroll 4
    for (int n = 0; n < NCH; n++) {
        float acc = 0.f;
#pragma unroll
        for (int i = 0; i < RD; i++) acc += q[i] * rb[n * RD + i];
        s[n] = acc;
        sc_out[(size_t)row * NCH + n] = acc;
    }
    unsigned mask = 0;
    for (int t = 0; t < TOPB; t++) {
        float best = -INFINITY;
        int bi = 0;
#pragma unroll
        for (int n = 0; n < NCH; n++) {
            const bool ok = !((mask >> n) & 1u) && (s[n] > best);
            if (ok) { best = s[n]; bi = n; }
        }
        mask |= (1u << bi);
        idx_out[(size_t)row * TOPB + t] = (float)bi;
    }
}

// ---------------------------------------------------------------------------
// Flash causal attention, fp32, 64x64 tiles. One block per (qtile, h, b).
// 256 threads: thread t handles row r=t>>2, dim-group cg=t&3 (16 dims).
// ---------------------------------------------------------------------------
__global__ __launch_bounds__(256) void attn_kernel(
    const float* __restrict__ q, const float* __restrict__ k,
    const float* __restrict__ v, float* __restrict__ y)
{
    const int qt = blockIdx.x, h = blockIdx.y, b = blockIdx.z;
    const int tid = threadIdx.x;
    const int r  = tid >> 2;
    const int cg = tid & 3;

    __shared__ float Qs[64][65], Ks[64][65], Vs[64][65], Ps[64][65];
    __shared__ float redm[64][4], reds[64][4];

    const size_t base = ((size_t)(b * H_ + h) * T_) * D_;

    // load Q tile
#pragma unroll
    for (int it = 0; it < 4; it++) {
        const int idx = tid + it * 256;      // float4 index
        const int rr = idx >> 4, dd = (idx & 15) * 4;
        *(float4*)&Qs[rr][dd] = *(const float4*)&q[base + (size_t)(qt * 64 + rr) * D_ + dd];
    }

    float m_old = -INFINITY, l = 0.f;
    float acc[16];
#pragma unroll
    for (int j = 0; j < 16; j++) acc[j] = 0.f;
    const float scale = 0.125f;   // 1/sqrt(64)

    for (int kt = 0; kt <= qt; ++kt) {
        __syncthreads();
#pragma unroll
        for (int it = 0; it < 4; it++) {
            const int idx = tid + it * 256;
            const int rr = idx >> 4, dd = (idx & 15) * 4;
            *(float4*)&Ks[rr][dd] = *(const float4*)&k[base + (size_t)(kt * 64 + rr) * D_ + dd];
            *(float4*)&Vs[rr][dd] = *(const float4*)&v[base + (size_t)(kt * 64 + rr) * D_ + dd];
        }
        __syncthreads();

        float s[16];
        float tmax = -INFINITY;
        const int qg = qt * 64 + r;
#pragma unroll
        for (int i = 0; i < 16; i++) {
            const int kk = cg * 16 + i;
            float d0 = 0.f;
#pragma unroll
            for (int d = 0; d < 64; d += 4) {
                float4 qv = *(const float4*)&Qs[r][d];
                float4 kv = *(const float4*)&Ks[kk][d];
                d0 += qv.x * kv.x + qv.y * kv.y + qv.z * kv.z + qv.w * kv.w;
            }
            d0 *= scale;
            if (kt * 64 + kk > qg) d0 = -INFINITY;
            s[i] = d0;
            tmax = fmaxf(tmax, d0);
        }
        redm[r][cg] = tmax;
        __syncthreads();
        const float mt = fmaxf(fmaxf(redm[r][0], redm[r][1]), fmaxf(redm[r][2], redm[r][3]));
        const float m_new = fmaxf(m_old, mt);
        float ssum = 0.f;
#pragma unroll
        for (int i = 0; i < 16; i++) {
            const float p = expf(s[i] - m_new);
            Ps[r][cg * 16 + i] = p;
            ssum += p;
        }
        reds[r][cg] = ssum;
        const float f = expf(m_old - m_new);
        __syncthreads();
        const float tsum = reds[r][0] + reds[r][1] + reds[r][2] + reds[r][3];
        l = l * f + tsum;
        m_old = m_new;
#pragma unroll
        for (int j = 0; j < 16; j++) acc[j] *= f;
        // PV
        for (int kk2 = 0; kk2 < 64; kk2++) {
            const float p = Ps[r][kk2];
#pragma unroll
            for (int j = 0; j < 16; j += 4) {
                float4 vv = *(const float4*)&Vs[kk2][cg * 16 + j];
                acc[j + 0] += p * vv.x;
                acc[j + 1] += p * vv.y;
                acc[j + 2] += p * vv.z;
                acc[j + 3] += p * vv.w;
            }
        }
    }

    const float inv = 1.0f / l;
    const size_t yo = ((size_t)b * T_ + qt * 64 + r) * C_ + h * D_ + cg * 16;
#pragma unroll
    for (int j = 0; j < 16; j += 4) {
        float4 o;
        o.x = acc[j + 0] * inv;
        o.y = acc[j + 1] * inv;
        o.z = acc[j + 2] * inv;
        o.w = acc[j + 3] * inv;
        *(float4*)&y[yo + j] = o;
    }
}

// ---------------------------------------------------------------------------
extern "C" void kernel_launch(void* const* d_in, const int* in_sizes, int n_in,
                              void* d_out, int out_size, void* d_ws, size_t ws_size,
                              hipStream_t stream)
{
    const float* x       = (const float*)d_in[0];
    const float* Wqkv    = (const float*)d_in[1];
    const float* bqkv    = (const float*)d_in[2];
    const float* Wproj   = (const float*)d_in[3];
    const float* bproj   = (const float*)d_in[4];
    const float* Wrouter = (const float*)d_in[5];
    const float* brouter = (const float*)d_in[6];
    const float* Wq_rt   = (const float*)d_in[7];
    const float* bq_rt   = (const float*)d_in[8];

    float* out = (float*)d_out;
    float* ws  = (float*)d_ws;

    const size_t QKV = (size_t)B_ * H_ * T_ * D_;   // 4194304
    float* q   = ws;
    float* k   = ws + QKV;
    float* v   = ws + 2 * QKV;
    float* ya  = ws + 3 * QKV;                       // [B,T,C]
    float* cm  = ws + 4 * QKV;                       // [B,NCH,C]  65536
    float* qrt = cm + (size_t)B_ * NCH * C_;         // [B,T,RD]  131072
    float* ren = qrt + (size_t)B_ * T_ * RD;         // [B,NCH,RD] 2048

    float* y_out   = out;                            // B*T*C
    float* idx_out = out + (size_t)B_ * T_ * C_;     // B*T*TOPB
    float* sc_out  = idx_out + (size_t)B_ * T_ * TOPB;  // B*T*NCH
    float* emb_out = sc_out + (size_t)B_ * T_ * NCH;    // B*NCH*RD

    // 1) qkv projection -> q,k,v [B,H,T,D]
    gemm128<1><<<dim3(3 * C_ / 128, B_ * T_ / 128), 256, 0, stream>>>(
        x, Wqkv, bqkv, nullptr, B_ * T_, 3 * C_, C_, q, k, v);

    // 2) routing path
    chunk_mean_kernel<<<B_ * NCH, 256, 0, stream>>>(x, cm);
    rowgemm32<<<(B_ * NCH + 7) / 8, 256, 0, stream>>>(cm, Wrouter, brouter, emb_out, B_ * NCH, 0);
    l2norm_rows<<<(B_ * NCH + 7) / 8, 256, 0, stream>>>(emb_out, ren, B_ * NCH);
    rowgemm32<<<(B_ * T_ + 7) / 8, 256, 0, stream>>>(x, Wq_rt, bq_rt, qrt, B_ * T_, 1);
    scores_topk<<<(B_ * T_ + 255) / 256, 256, 0, stream>>>(qrt, ren, sc_out, idx_out);

    // 3) dense causal attention -> ya [B,T,C]
    attn_kernel<<<dim3(T_ / 64, H_, B_), 256, 0, stream>>>(q, k, v, ya);

    // 4) output projection -> y
    gemm128<0><<<dim3(C_ / 128, B_ * T_ / 128), 256, 0, stream>>>(
        ya, Wproj, bproj, y_out, B_ * T_, C_, C_, nullptr, nullptr, nullptr);
}

// Round 2
// 702.514 us; speedup vs baseline: 3.2823x; 3.2823x over previous
//
#include <hip/hip_runtime.h>
#include <hip/hip_bf16.h>
#include <math.h>

#define B_   2
#define T_   2048
#define C_   1024
#define H_   16
#define D_   64
#define NCH  32
#define RD   32
#define TOPB 8

typedef __attribute__((ext_vector_type(8))) short bf16x8;
typedef __attribute__((ext_vector_type(4))) float f32x4;

// ---------------------------------------------------------------------------
// Tiled fp32 GEMM: out = A[M,K] @ Bm[K,N] + bias[N]
// MODE 0: plain row-major f32 write to out[M,N]
// MODE 1: qkv scatter: col -> (which, h, d), row -> (b, t); write bf16 [B,H,T,D]
// ---------------------------------------------------------------------------
template <int MODE>
__global__ __launch_bounds__(256) void gemm128(
    const float* __restrict__ A, const float* __restrict__ Bm,
    const float* __restrict__ bias, float* __restrict__ out,
    int M, int N, int K,
    __hip_bfloat16* __restrict__ qp, __hip_bfloat16* __restrict__ kp,
    __hip_bfloat16* __restrict__ vp)
{
    __shared__ float As[8][128];
    __shared__ float Bs[8][128];

    const int tid = threadIdx.x;
    const int n0 = blockIdx.x * 128;
    const int m0 = blockIdx.y * 128;
    const int tx = tid & 15;
    const int ty = tid >> 4;

    const int ar = tid >> 1;
    const int ak = (tid & 1) * 4;
    const int bk = tid >> 5;
    const int bn = (tid & 31) * 4;

    float acc[8][8];
#pragma unroll
    for (int i = 0; i < 8; i++)
#pragma unroll
        for (int j = 0; j < 8; j++) acc[i][j] = 0.f;

    for (int k0 = 0; k0 < K; k0 += 8) {
        float4 av = *(const float4*)&A[(size_t)(m0 + ar) * K + k0 + ak];
        float4 bv = *(const float4*)&Bm[(size_t)(k0 + bk) * N + n0 + bn];
        __syncthreads();
        As[ak + 0][ar] = av.x;
        As[ak + 1][ar] = av.y;
        As[ak + 2][ar] = av.z;
        As[ak + 3][ar] = av.w;
        *(float4*)&Bs[bk][bn] = bv;
        __syncthreads();
#pragma unroll
        for (int kk = 0; kk < 8; kk++) {
            float a[8], b[8];
            *(float4*)&a[0] = *(const float4*)&As[kk][ty * 8];
            *(float4*)&a[4] = *(const float4*)&As[kk][ty * 8 + 4];
            *(float4*)&b[0] = *(const float4*)&Bs[kk][tx * 8];
            *(float4*)&b[4] = *(const float4*)&Bs[kk][tx * 8 + 4];
#pragma unroll
            for (int i = 0; i < 8; i++)
#pragma unroll
                for (int j = 0; j < 8; j++) acc[i][j] += a[i] * b[j];
        }
    }

#pragma unroll
    for (int i = 0; i < 8; i++) {
        const int row = m0 + ty * 8 + i;
#pragma unroll
        for (int j = 0; j < 8; j++) {
            const int col = n0 + tx * 8 + j;
            const float vl = acc[i][j] + bias[col];
            if (MODE == 0) {
                out[(size_t)row * N + col] = vl;
            } else {
                const int which = col >> 10;     // 0=q 1=k 2=v
                const int c  = col & 1023;
                const int hh = c >> 6;
                const int dd = c & 63;
                const int bb = row >> 11;
                const int tt = row & 2047;
                __hip_bfloat16* dst = (which == 0) ? qp : (which == 1) ? kp : vp;
                dst[(((size_t)bb * H_ + hh) * T_ + tt) * D_ + dd] = __float2bfloat16(vl);
            }
        }
    }
}

// ---------------------------------------------------------------------------
// chunk means: x[B,T,C] -> cm[B,NCH,C]
// ---------------------------------------------------------------------------
__global__ void chunk_mean_kernel(const float* __restrict__ x, float* __restrict__ cm)
{
    const int bc = blockIdx.x;
    const int b = bc >> 5, n = bc & 31;
    const float* xp = x + ((size_t)b * T_ + n * 64) * C_;
    for (int c = threadIdx.x; c < C_; c += blockDim.x) {
        float s = 0.f;
        for (int i = 0; i < 64; i++) s += xp[(size_t)i * C_ + c];
        cm[(size_t)bc * C_ + c] = s * (1.0f / 64.0f);
    }
}

// ---------------------------------------------------------------------------
// rowgemm32
// ---------------------------------------------------------------------------
__global__ void rowgemm32(const float* __restrict__ A, const float* __restrict__ W,
                          const float* __restrict__ bias, float* __restrict__ dst,
                          int M, int normalize)
{
    const int row  = blockIdx.x * 8 + (threadIdx.x >> 5);
    const int lane = threadIdx.x & 31;
    if (row >= M) return;
    const float* a = A + (size_t)row * C_;
    float acc = 0.f;
    for (int k = 0; k < C_; k += 4) {
        float4 a4 = *(const float4*)&a[k];
        acc += a4.x * W[(k + 0) * RD + lane];
        acc += a4.y * W[(k + 1) * RD + lane];
        acc += a4.z * W[(k + 2) * RD + lane];
        acc += a4.w * W[(k + 3) * RD + lane];
    }
    acc += bias[lane];
    if (normalize) {
        float ss = acc * acc;
#pragma unroll
        for (int off = 16; off >= 1; off >>= 1) ss += __shfl_xor(ss, off, 32);
        acc = acc / fmaxf(sqrtf(ss), 1e-12f);
    }
    dst[(size_t)row * RD + lane] = acc;
}

__global__ void l2norm_rows(const float* __restrict__ src, float* __restrict__ dst, int M)
{
    const int row  = blockIdx.x * 8 + (threadIdx.x >> 5);
    const int lane = threadIdx.x & 31;
    if (row >= M) return;
    float v = src[(size_t)row * RD + lane];
    float ss = v * v;
#pragma unroll
    for (int off = 16; off >= 1; off >>= 1) ss += __shfl_xor(ss, off, 32);
    dst[(size_t)row * RD + lane] = v / fmaxf(sqrtf(ss), 1e-12f);
}

// ---------------------------------------------------------------------------
// routing scores + top-8 (lax.top_k tie-break: lower index wins)
// ---------------------------------------------------------------------------
__global__ void scores_topk(const float* __restrict__ qrt, const float* __restrict__ ren,
                            float* __restrict__ sc_out, float* __restrict__ idx_out)
{
    const int row = blockIdx.x * blockDim.x + threadIdx.x;
    if (row >= B_ * T_) return;
    const int b = row / T_;
    float q[RD];
#pragma unroll
    for (int i = 0; i < RD; i++) q[i] = qrt[(size_t)row * RD + i];
    const float* rb = ren + (size_t)b * NCH * RD;
    float s[NCH];
#pragma unroll 4
    for (int n = 0; n < NCH; n++) {
        float acc = 0.f;
#pragma unroll
        for (int i = 0; i < RD; i++) acc += q[i] * rb[n * RD + i];
        s[n] = acc;
        sc_out[(size_t)row * NCH + n] = acc;
    }
    unsigned mask = 0;
    for (int t = 0; t < TOPB; t++) {
        float best = -INFINITY;
        int bi = 0;
#pragma unroll
        for (int n = 0; n < NCH; n++) {
            const bool ok = !((mask >> n) & 1u) && (s[n] > best);
            if (ok) { best = s[n]; bi = n; }
        }
        mask |= (1u << bi);
        idx_out[(size_t)row * TOPB + t] = (float)bi;
    }
}

// ---------------------------------------------------------------------------
// MFMA bf16 flash attention. Block = 64 q-rows of one (b,h), 4 waves x 16 rows.
// mfma_f32_16x16x32_bf16: A[m=l&15][k=(l>>4)*8+j], B[k=(l>>4)*8+j][n=l&15],
// C/D: col=l&15, row=(l>>4)*4+reg  (verified layout).
// ---------------------------------------------------------------------------
__global__ __launch_bounds__(256) void attn_mfma(
    const __hip_bfloat16* __restrict__ qg, const __hip_bfloat16* __restrict__ kg,
    const __hip_bfloat16* __restrict__ vg, float* __restrict__ y)
{
    const int qt = blockIdx.x, h = blockIdx.y, b = blockIdx.z;
    const int tid  = threadIdx.x;
    const int wave = tid >> 6;
    const int lane = tid & 63;
    const int lg = lane >> 4;     // k-group / row-group
    const int lr = lane & 15;     // col / row-in-16

    __shared__ short Ks[64][72];
    __shared__ short Vt[64][72];        // Vt[d][kv]
    __shared__ short Ps[4][16][72];     // per-wave P tile

    const size_t base = ((size_t)(b * H_ + h) * T_) * D_;

    // Q fragments, hoisted (wave's 16 rows)
    bf16x8 qf[2];
    {
        const int qrow = qt * 64 + wave * 16 + lr;
        const short* qp = (const short*)qg + base + (size_t)qrow * D_;
        qf[0] = *(const bf16x8*)&qp[lg * 8];
        qf[1] = *(const bf16x8*)&qp[32 + lg * 8];
    }

    float m_run[4], l_run[4];
    f32x4 oacc[4];
#pragma unroll
    for (int r = 0; r < 4; r++) {
        m_run[r] = -INFINITY;
        l_run[r] = 0.f;
        oacc[r] = (f32x4){0.f, 0.f, 0.f, 0.f};
    }

    const int nkt = qt + 1;
    for (int kt = 0; kt < nkt; ++kt) {
        __syncthreads();
        // stage K (row-major) and V (transposed) tiles
        {
            const int rr = tid >> 2;
            const int c0 = (tid & 3) * 16;
            const short* kp = (const short*)kg + base + (size_t)(kt * 64 + rr) * D_ + c0;
            bf16x8 k0 = *(const bf16x8*)kp;
            bf16x8 k1 = *(const bf16x8*)(kp + 8);
            *(bf16x8*)&Ks[rr][c0]     = k0;
            *(bf16x8*)&Ks[rr][c0 + 8] = k1;
            const short* vp = (const short*)vg + base + (size_t)(kt * 64 + rr) * D_ + c0;
            bf16x8 v0 = *(const bf16x8*)vp;
            bf16x8 v1 = *(const bf16x8*)(vp + 8);
#pragma unroll
            for (int j = 0; j < 8; j++) Vt[c0 + j][rr]     = v0[j];
#pragma unroll
            for (int j = 0; j < 8; j++) Vt[c0 + 8 + j][rr] = v1[j];
        }
        __syncthreads();

        // QK^T: 4 column blocks of 16
        f32x4 s[4];
#pragma unroll
        for (int cb = 0; cb < 4; cb++) {
            bf16x8 kf0 = *(const bf16x8*)&Ks[cb * 16 + lr][lg * 8];
            bf16x8 kf1 = *(const bf16x8*)&Ks[cb * 16 + lr][32 + lg * 8];
            f32x4 acc = (f32x4){0.f, 0.f, 0.f, 0.f};
            acc = __builtin_amdgcn_mfma_f32_16x16x32_bf16(qf[0], kf0, acc, 0, 0, 0);
            acc = __builtin_amdgcn_mfma_f32_16x16x32_bf16(qf[1], kf1, acc, 0, 0, 0);
            s[cb] = acc;
        }

        // scale + causal mask (only the diagonal tile needs masking)
        const int row0 = qt * 64 + wave * 16 + lg * 4;
        if (kt == nkt - 1) {
#pragma unroll
            for (int cb = 0; cb < 4; cb++) {
                const int col_g = kt * 64 + cb * 16 + lr;
#pragma unroll
                for (int r = 0; r < 4; r++) {
                    float sv = s[cb][r] * 0.125f;
                    if (col_g > row0 + r) sv = -INFINITY;
                    s[cb][r] = sv;
                }
            }
        } else {
#pragma unroll
            for (int cb = 0; cb < 4; cb++)
#pragma unroll
                for (int r = 0; r < 4; r++) s[cb][r] *= 0.125f;
        }

        // per-row max (over 4 col blocks, then 16 lanes of the group)
        float rm[4];
#pragma unroll
        for (int r = 0; r < 4; r++)
            rm[r] = fmaxf(fmaxf(s[0][r], s[1][r]), fmaxf(s[2][r], s[3][r]));
#pragma unroll
        for (int off = 1; off <= 8; off <<= 1)
#pragma unroll
            for (int r = 0; r < 4; r++) rm[r] = fmaxf(rm[r], __shfl_xor(rm[r], off));

        float mnew[4], fsc[4];
#pragma unroll
        for (int r = 0; r < 4; r++) {
            mnew[r] = fmaxf(m_run[r], rm[r]);
            fsc[r]  = __expf(m_run[r] - mnew[r]);   // exp(-inf)=0 on first tile
            m_run[r] = mnew[r];
        }

        // P = exp(S - m), store bf16 to wave-private LDS, accumulate row sums
        float rs[4] = {0.f, 0.f, 0.f, 0.f};
#pragma unroll
        for (int cb = 0; cb < 4; cb++) {
#pragma unroll
            for (int r = 0; r < 4; r++) {
                const float p = __expf(s[cb][r] - mnew[r]);
                rs[r] += p;
                Ps[wave][lg * 4 + r][cb * 16 + lr] = (short)__bfloat16_as_ushort(__float2bfloat16(p));
            }
        }
#pragma unroll
        for (int off = 1; off <= 8; off <<= 1)
#pragma unroll
            for (int r = 0; r < 4; r++) rs[r] += __shfl_xor(rs[r], off);
#pragma unroll
        for (int r = 0; r < 4; r++) l_run[r] = l_run[r] * fsc[r] + rs[r];

        // rescale accumulator
#pragma unroll
        for (int db = 0; db < 4; db++)
#pragma unroll
            for (int r = 0; r < 4; r++) oacc[db][r] *= fsc[r];

        // PV: A = P (from LDS), B = Vt rows (contiguous)
        bf16x8 pf0 = *(const bf16x8*)&Ps[wave][lr][lg * 8];
        bf16x8 pf1 = *(const bf16x8*)&Ps[wave][lr][32 + lg * 8];
#pragma unroll
        for (int db = 0; db < 4; db++) {
            bf16x8 vf0 = *(const bf16x8*)&Vt[db * 16 + lr][lg * 8];
            bf16x8 vf1 = *(const bf16x8*)&Vt[db * 16 + lr][32 + lg * 8];
            oacc[db] = __builtin_amdgcn_mfma_f32_16x16x32_bf16(pf0, vf0, oacc[db], 0, 0, 0);
            oacc[db] = __builtin_amdgcn_mfma_f32_16x16x32_bf16(pf1, vf1, oacc[db], 0, 0, 0);
        }
    }

    // epilogue: O / l -> y[B,T,C]
#pragma unroll
    for (int r = 0; r < 4; r++) {
        const float inv = 1.0f / l_run[r];
        const int trow = qt * 64 + wave * 16 + lg * 4 + r;
        float* yp = y + (size_t)(b * T_ + trow) * C_ + h * D_;
#pragma unroll
        for (int db = 0; db < 4; db++)
            yp[db * 16 + lr] = oacc[db][r] * inv;
    }
}

// ---------------------------------------------------------------------------
extern "C" void kernel_launch(void* const* d_in, const int* in_sizes, int n_in,
                              void* d_out, int out_size, void* d_ws, size_t ws_size,
                              hipStream_t stream)
{
    const float* x       = (const float*)d_in[0];
    const float* Wqkv    = (const float*)d_in[1];
    const float* bqkv    = (const float*)d_in[2];
    const float* Wproj   = (const float*)d_in[3];
    const float* bproj   = (const float*)d_in[4];
    const float* Wrouter = (const float*)d_in[5];
    const float* brouter = (const float*)d_in[6];
    const float* Wq_rt   = (const float*)d_in[7];
    const float* bq_rt   = (const float*)d_in[8];

    float* out = (float*)d_out;
    char*  ws  = (char*)d_ws;

    const size_t QKV = (size_t)B_ * H_ * T_ * D_;   // 4 Mi elements

    __hip_bfloat16* q = (__hip_bfloat16*)ws;                         // 8 MB
    __hip_bfloat16* k = (__hip_bfloat16*)(ws + QKV * 2);             // 8 MB
    __hip_bfloat16* v = (__hip_bfloat16*)(ws + QKV * 4);             // 8 MB
    float* ya  = (float*)(ws + QKV * 6);                             // 16 MB
    float* cm  = ya  + (size_t)B_ * T_ * C_;
    float* qrt = cm  + (size_t)B_ * NCH * C_;
    float* ren = qrt + (size_t)B_ * T_ * RD;

    float* y_out   = out;
    float* idx_out = out + (size_t)B_ * T_ * C_;
    float* sc_out  = idx_out + (size_t)B_ * T_ * TOPB;
    float* emb_out = sc_out + (size_t)B_ * T_ * NCH;

    // 1) qkv projection -> bf16 q,k,v [B,H,T,D]
    gemm128<1><<<dim3(3 * C_ / 128, B_ * T_ / 128), 256, 0, stream>>>(
        x, Wqkv, bqkv, nullptr, B_ * T_, 3 * C_, C_, q, k, v);

    // 2) routing path
    chunk_mean_kernel<<<B_ * NCH, 256, 0, stream>>>(x, cm);
    rowgemm32<<<(B_ * NCH + 7) / 8, 256, 0, stream>>>(cm, Wrouter, brouter, emb_out, B_ * NCH, 0);
    l2norm_rows<<<(B_ * NCH + 7) / 8, 256, 0, stream>>>(emb_out, ren, B_ * NCH);
    rowgemm32<<<(B_ * T_ + 7) / 8, 256, 0, stream>>>(x, Wq_rt, bq_rt, qrt, B_ * T_, 1);
    scores_topk<<<(B_ * T_ + 255) / 256, 256, 0, stream>>>(qrt, ren, sc_out, idx_out);

    // 3) MFMA flash attention -> ya [B,T,C]
    attn_mfma<<<dim3(T_ / 64, H_, B_), 256, 0, stream>>>(q, k, v, ya);

    // 4) output projection
    gemm128<0><<<dim3(C_ / 128, B_ * T_ / 128), 256, 0, stream>>>(
        ya, Wproj, bproj, y_out, B_ * T_, C_, C_, nullptr, nullptr, nullptr);
}

// Round 3
// 322.448 us; speedup vs baseline: 7.1512x; 2.1787x over previous
//
#include <hip/hip_runtime.h>
#include <hip/hip_bf16.h>
#include <math.h>

#define B_   2
#define T_   2048
#define C_   1024
#define H_   16
#define D_   64
#define NCH  32
#define RD   32
#define TOPB 8

typedef __attribute__((ext_vector_type(8))) short bf16x8;
typedef __attribute__((ext_vector_type(4))) float f32x4;

static __device__ __forceinline__ unsigned short f2b(float f) {
    return __bfloat16_as_ushort(__float2bfloat16(f));
}

// ---------------------------------------------------------------------------
// cast x (f32) -> bf16, 8 elements per thread
// ---------------------------------------------------------------------------
__global__ __launch_bounds__(256) void cast_bf16_kernel(
    const float* __restrict__ in, unsigned short* __restrict__ out, int n8)
{
    const int i = blockIdx.x * blockDim.x + threadIdx.x;
    if (i >= n8) return;
    float4 a = ((const float4*)in)[i * 2];
    float4 b = ((const float4*)in)[i * 2 + 1];
    bf16x8 o;
    o[0] = (short)f2b(a.x); o[1] = (short)f2b(a.y);
    o[2] = (short)f2b(a.z); o[3] = (short)f2b(a.w);
    o[4] = (short)f2b(b.x); o[5] = (short)f2b(b.y);
    o[6] = (short)f2b(b.z); o[7] = (short)f2b(b.w);
    *(bf16x8*)&out[i * 8] = o;
}

// ---------------------------------------------------------------------------
// W [K][N] f32 -> Wt [N][K] bf16, 64x64 tiles via LDS
// ---------------------------------------------------------------------------
__global__ __launch_bounds__(256) void transpose_cast_kernel(
    const float* __restrict__ W, unsigned short* __restrict__ Wt, int K, int N)
{
    __shared__ float t[64][65];
    const int tid = threadIdx.x;
    const int n0 = blockIdx.x * 64, k0 = blockIdx.y * 64;
#pragma unroll
    for (int i = 0; i < 4; i++) {
        const int f = tid + i * 256;       // float4 slot
        const int r = f >> 4, c4 = (f & 15) * 4;
        float4 v = *(const float4*)&W[(size_t)(k0 + r) * N + n0 + c4];
        t[r][c4 + 0] = v.x; t[r][c4 + 1] = v.y;
        t[r][c4 + 2] = v.z; t[r][c4 + 3] = v.w;
    }
    __syncthreads();
#pragma unroll
    for (int i = 0; i < 2; i++) {
        const int s = tid + i * 256;       // 8-elem slot
        const int rn = s >> 3, ck8 = (s & 7) * 8;
        bf16x8 o;
#pragma unroll
        for (int j = 0; j < 8; j++) o[j] = (short)f2b(t[ck8 + j][rn]);
        *(bf16x8*)&Wt[(size_t)(n0 + rn) * K + k0 + ck8] = o;
    }
}

// ---------------------------------------------------------------------------
// bf16 MFMA GEMM (m97 structure): C = A[M,K] @ Bt[N,K]^T + bias
// 128x128 tile, BK=32, 256 threads = 4 waves (2x2), 64x64 per wave.
// MODE 0: f32 out[M,N].  MODE 1: qkv scatter -> bf16 [B,H,T,D].
// ---------------------------------------------------------------------------
template <int MODE>
__global__ __launch_bounds__(256) void gemm_mfma(
    const unsigned short* __restrict__ A, const unsigned short* __restrict__ Bt,
    const float* __restrict__ bias, float* __restrict__ out,
    unsigned short* __restrict__ qp, unsigned short* __restrict__ kp,
    unsigned short* __restrict__ vp, int M, int N, int K)
{
    __shared__ unsigned short As[128 * 32];
    __shared__ unsigned short Bs[128 * 32];

    const int tid  = threadIdx.x;
    const int lane = tid & 63;
    const int wave = tid >> 6;
    const int lr = lane & 15, lg = lane >> 4;
    const int wm = wave >> 1, wn = wave & 1;
    const int n0 = blockIdx.x * 128, m0 = blockIdx.y * 128;

    const int srow = tid >> 2;            // staging row 0..63
    const int scol = (tid & 3) * 8;       // staging k-offset
    const unsigned short* ga = A  + (size_t)(m0 + srow) * K + scol;
    const unsigned short* gb = Bt + (size_t)(n0 + srow) * K + scol;
    const int ldst = (tid & 0xC0) * 8;    // wave-uniform base (elements), +i*2048

    f32x4 acc[4][4];
#pragma unroll
    for (int i = 0; i < 4; i++)
#pragma unroll
        for (int j = 0; j < 4; j++) acc[i][j] = (f32x4){0.f, 0.f, 0.f, 0.f};

    for (int k0 = 0; k0 < K; k0 += 32) {
        __syncthreads();
#pragma unroll
        for (int i = 0; i < 2; i++) {
            __builtin_amdgcn_global_load_lds(
                (const __attribute__((address_space(1))) int*)(ga + k0 + (size_t)i * 64 * K),
                (__attribute__((address_space(3))) int*)&As[i * 2048 + ldst], 16, 0, 0);
            __builtin_amdgcn_global_load_lds(
                (const __attribute__((address_space(1))) int*)(gb + k0 + (size_t)i * 64 * K),
                (__attribute__((address_space(3))) int*)&Bs[i * 2048 + ldst], 16, 0, 0);
        }
        __syncthreads();

        bf16x8 af[4], bfr[4];
#pragma unroll
        for (int mi = 0; mi < 4; mi++)
            af[mi] = *(const bf16x8*)&As[(wm * 64 + mi * 16 + lr) * 32 + lg * 8];
#pragma unroll
        for (int ni = 0; ni < 4; ni++)
            bfr[ni] = *(const bf16x8*)&Bs[(wn * 64 + ni * 16 + lr) * 32 + lg * 8];
#pragma unroll
        for (int mi = 0; mi < 4; mi++)
#pragma unroll
            for (int ni = 0; ni < 4; ni++)
                acc[mi][ni] = __builtin_amdgcn_mfma_f32_16x16x32_bf16(
                    af[mi], bfr[ni], acc[mi][ni], 0, 0, 0);
    }

    // epilogue: C/D layout col=lane&15, row=(lane>>4)*4+reg
#pragma unroll
    for (int ni = 0; ni < 4; ni++) {
        const int col = n0 + wn * 64 + ni * 16 + lr;
        const float bv = bias[col];
        if (MODE == 0) {
#pragma unroll
            for (int mi = 0; mi < 4; mi++) {
#pragma unroll
                for (int r = 0; r < 4; r++) {
                    const int row = m0 + wm * 64 + mi * 16 + lg * 4 + r;
                    out[(size_t)row * N + col] = acc[mi][ni][r] + bv;
                }
            }
        } else {
            const int which = col >> 10;
            const int c  = col & 1023;
            const int hh = c >> 6;
            const int dd = c & 63;
            unsigned short* dst = (which == 0) ? qp : (which == 1) ? kp : vp;
#pragma unroll
            for (int mi = 0; mi < 4; mi++) {
#pragma unroll
                for (int r = 0; r < 4; r++) {
                    const int row = m0 + wm * 64 + mi * 16 + lg * 4 + r;
                    const int bb = row >> 11, tt = row & 2047;
                    dst[(((size_t)bb * H_ + hh) * T_ + tt) * D_ + dd] =
                        f2b(acc[mi][ni][r] + bv);
                }
            }
        }
    }
}

// ---------------------------------------------------------------------------
// chunk means: x[B,T,C] -> cm[B,NCH,C]
// ---------------------------------------------------------------------------
__global__ void chunk_mean_kernel(const float* __restrict__ x, float* __restrict__ cm)
{
    const int bc = blockIdx.x;
    const int b = bc >> 5, n = bc & 31;
    const float* xp = x + ((size_t)b * T_ + n * 64) * C_;
    for (int c = threadIdx.x; c < C_; c += blockDim.x) {
        float s = 0.f;
        for (int i = 0; i < 64; i++) s += xp[(size_t)i * C_ + c];
        cm[(size_t)bc * C_ + c] = s * (1.0f / 64.0f);
    }
}

// ---------------------------------------------------------------------------
// rowgemm32
// ---------------------------------------------------------------------------
__global__ void rowgemm32(const float* __restrict__ A, const float* __restrict__ W,
                          const float* __restrict__ bias, float* __restrict__ dst,
                          int M, int normalize)
{
    const int row  = blockIdx.x * 8 + (threadIdx.x >> 5);
    const int lane = threadIdx.x & 31;
    if (row >= M) return;
    const float* a = A + (size_t)row * C_;
    float acc = 0.f;
    for (int k = 0; k < C_; k += 4) {
        float4 a4 = *(const float4*)&a[k];
        acc += a4.x * W[(k + 0) * RD + lane];
        acc += a4.y * W[(k + 1) * RD + lane];
        acc += a4.z * W[(k + 2) * RD + lane];
        acc += a4.w * W[(k + 3) * RD + lane];
    }
    acc += bias[lane];
    if (normalize) {
        float ss = acc * acc;
#pragma unroll
        for (int off = 16; off >= 1; off >>= 1) ss += __shfl_xor(ss, off, 32);
        acc = acc / fmaxf(sqrtf(ss), 1e-12f);
    }
    dst[(size_t)row * RD + lane] = acc;
}

__global__ void l2norm_rows(const float* __restrict__ src, float* __restrict__ dst, int M)
{
    const int row  = blockIdx.x * 8 + (threadIdx.x >> 5);
    const int lane = threadIdx.x & 31;
    if (row >= M) return;
    float v = src[(size_t)row * RD + lane];
    float ss = v * v;
#pragma unroll
    for (int off = 16; off >= 1; off >>= 1) ss += __shfl_xor(ss, off, 32);
    dst[(size_t)row * RD + lane] = v / fmaxf(sqrtf(ss), 1e-12f);
}

// ---------------------------------------------------------------------------
// routing scores + top-8 (lax.top_k tie-break: lower index wins)
// ---------------------------------------------------------------------------
__global__ void scores_topk(const float* __restrict__ qrt, const float* __restrict__ ren,
                            float* __restrict__ sc_out, float* __restrict__ idx_out)
{
    const int row = blockIdx.x * blockDim.x + threadIdx.x;
    if (row >= B_ * T_) return;
    const int b = row / T_;
    float q[RD];
#pragma unroll
    for (int i = 0; i < RD; i++) q[i] = qrt[(size_t)row * RD + i];
    const float* rb = ren + (size_t)b * NCH * RD;
    float s[NCH];
#pragma unroll 4
    for (int n = 0; n < NCH; n++) {
        float acc = 0.f;
#pragma unroll
        for (int i = 0; i < RD; i++) acc += q[i] * rb[n * RD + i];
        s[n] = acc;
        sc_out[(size_t)row * NCH + n] = acc;
    }
    unsigned mask = 0;
    for (int t = 0; t < TOPB; t++) {
        float best = -INFINITY;
        int bi = 0;
#pragma unroll
        for (int n = 0; n < NCH; n++) {
            const bool ok = !((mask >> n) & 1u) && (s[n] > best);
            if (ok) { best = s[n]; bi = n; }
        }
        mask |= (1u << bi);
        idx_out[(size_t)row * TOPB + t] = (float)bi;
    }
}

// ---------------------------------------------------------------------------
// MFMA bf16 flash attention. Block = 64 q-rows of one (b,h), 4 waves x 16 rows.
// Output written as bf16 [B,T,C] (feeds proj GEMM).
// ---------------------------------------------------------------------------
__global__ __launch_bounds__(256) void attn_mfma(
    const unsigned short* __restrict__ qg, const unsigned short* __restrict__ kg,
    const unsigned short* __restrict__ vg, unsigned short* __restrict__ y)
{
    const int qt = blockIdx.x, h = blockIdx.y, b = blockIdx.z;
    const int tid  = threadIdx.x;
    const int wave = tid >> 6;
    const int lane = tid & 63;
    const int lg = lane >> 4;
    const int lr = lane & 15;

    __shared__ short Ks[64][72];
    __shared__ short Vt[64][72];
    __shared__ short Ps[4][16][72];

    const size_t base = ((size_t)(b * H_ + h) * T_) * D_;

    bf16x8 qf[2];
    {
        const int qrow = qt * 64 + wave * 16 + lr;
        const short* qp = (const short*)qg + base + (size_t)qrow * D_;
        qf[0] = *(const bf16x8*)&qp[lg * 8];
        qf[1] = *(const bf16x8*)&qp[32 + lg * 8];
    }

    float m_run[4], l_run[4];
    f32x4 oacc[4];
#pragma unroll
    for (int r = 0; r < 4; r++) {
        m_run[r] = -INFINITY;
        l_run[r] = 0.f;
        oacc[r] = (f32x4){0.f, 0.f, 0.f, 0.f};
    }

    const int nkt = qt + 1;
    for (int kt = 0; kt < nkt; ++kt) {
        __syncthreads();
        {
            const int rr = tid >> 2;
            const int c0 = (tid & 3) * 16;
            const short* kp = (const short*)kg + base + (size_t)(kt * 64 + rr) * D_ + c0;
            bf16x8 k0 = *(const bf16x8*)kp;
            bf16x8 k1 = *(const bf16x8*)(kp + 8);
            *(bf16x8*)&Ks[rr][c0]     = k0;
            *(bf16x8*)&Ks[rr][c0 + 8] = k1;
            const short* vp = (const short*)vg + base + (size_t)(kt * 64 + rr) * D_ + c0;
            bf16x8 v0 = *(const bf16x8*)vp;
            bf16x8 v1 = *(const bf16x8*)(vp + 8);
#pragma unroll
            for (int j = 0; j < 8; j++) Vt[c0 + j][rr]     = v0[j];
#pragma unroll
            for (int j = 0; j < 8; j++) Vt[c0 + 8 + j][rr] = v1[j];
        }
        __syncthreads();

        f32x4 s[4];
#pragma unroll
        for (int cb = 0; cb < 4; cb++) {
            bf16x8 kf0 = *(const bf16x8*)&Ks[cb * 16 + lr][lg * 8];
            bf16x8 kf1 = *(const bf16x8*)&Ks[cb * 16 + lr][32 + lg * 8];
            f32x4 acc = (f32x4){0.f, 0.f, 0.f, 0.f};
            acc = __builtin_amdgcn_mfma_f32_16x16x32_bf16(qf[0], kf0, acc, 0, 0, 0);
            acc = __builtin_amdgcn_mfma_f32_16x16x32_bf16(qf[1], kf1, acc, 0, 0, 0);
            s[cb] = acc;
        }

        const int row0 = qt * 64 + wave * 16 + lg * 4;
        if (kt == nkt - 1) {
#pragma unroll
            for (int cb = 0; cb < 4; cb++) {
                const int col_g = kt * 64 + cb * 16 + lr;
#pragma unroll
                for (int r = 0; r < 4; r++) {
                    float sv = s[cb][r] * 0.125f;
                    if (col_g > row0 + r) sv = -INFINITY;
                    s[cb][r] = sv;
                }
            }
        } else {
#pragma unroll
            for (int cb = 0; cb < 4; cb++)
#pragma unroll
                for (int r = 0; r < 4; r++) s[cb][r] *= 0.125f;
        }

        float rm[4];
#pragma unroll
        for (int r = 0; r < 4; r++)
            rm[r] = fmaxf(fmaxf(s[0][r], s[1][r]), fmaxf(s[2][r], s[3][r]));
#pragma unroll
        for (int off = 1; off <= 8; off <<= 1)
#pragma unroll
            for (int r = 0; r < 4; r++) rm[r] = fmaxf(rm[r], __shfl_xor(rm[r], off));

        float mnew[4], fsc[4];
#pragma unroll
        for (int r = 0; r < 4; r++) {
            mnew[r] = fmaxf(m_run[r], rm[r]);
            fsc[r]  = __expf(m_run[r] - mnew[r]);
            m_run[r] = mnew[r];
        }

        float rs[4] = {0.f, 0.f, 0.f, 0.f};
#pragma unroll
        for (int cb = 0; cb < 4; cb++) {
#pragma unroll
            for (int r = 0; r < 4; r++) {
                const float p = __expf(s[cb][r] - mnew[r]);
                rs[r] += p;
                Ps[wave][lg * 4 + r][cb * 16 + lr] = (short)f2b(p);
            }
        }
#pragma unroll
        for (int off = 1; off <= 8; off <<= 1)
#pragma unroll
            for (int r = 0; r < 4; r++) rs[r] += __shfl_xor(rs[r], off);
#pragma unroll
        for (int r = 0; r < 4; r++) l_run[r] = l_run[r] * fsc[r] + rs[r];

#pragma unroll
        for (int db = 0; db < 4; db++)
#pragma unroll
            for (int r = 0; r < 4; r++) oacc[db][r] *= fsc[r];

        bf16x8 pf0 = *(const bf16x8*)&Ps[wave][lr][lg * 8];
        bf16x8 pf1 = *(const bf16x8*)&Ps[wave][lr][32 + lg * 8];
#pragma unroll
        for (int db = 0; db < 4; db++) {
            bf16x8 vf0 = *(const bf16x8*)&Vt[db * 16 + lr][lg * 8];
            bf16x8 vf1 = *(const bf16x8*)&Vt[db * 16 + lr][32 + lg * 8];
            oacc[db] = __builtin_amdgcn_mfma_f32_16x16x32_bf16(pf0, vf0, oacc[db], 0, 0, 0);
            oacc[db] = __builtin_amdgcn_mfma_f32_16x16x32_bf16(pf1, vf1, oacc[db], 0, 0, 0);
        }
    }

#pragma unroll
    for (int r = 0; r < 4; r++) {
        const float inv = 1.0f / l_run[r];
        const int trow = qt * 64 + wave * 16 + lg * 4 + r;
        unsigned short* yp = y + (size_t)(b * T_ + trow) * C_ + h * D_;
#pragma unroll
        for (int db = 0; db < 4; db++)
            yp[db * 16 + lr] = f2b(oacc[db][r] * inv);
    }
}

// ---------------------------------------------------------------------------
extern "C" void kernel_launch(void* const* d_in, const int* in_sizes, int n_in,
                              void* d_out, int out_size, void* d_ws, size_t ws_size,
                              hipStream_t stream)
{
    const float* x       = (const float*)d_in[0];
    const float* Wqkv    = (const float*)d_in[1];
    const float* bqkv    = (const float*)d_in[2];
    const float* Wproj   = (const float*)d_in[3];
    const float* bproj   = (const float*)d_in[4];
    const float* Wrouter = (const float*)d_in[5];
    const float* brouter = (const float*)d_in[6];
    const float* Wq_rt   = (const float*)d_in[7];
    const float* bq_rt   = (const float*)d_in[8];

    float* out = (float*)d_out;
    char*  ws  = (char*)d_ws;

    const size_t MT  = (size_t)B_ * T_;          // 4096
    const size_t QKV = MT * C_;                  // 4 Mi elems

    unsigned short* xb   = (unsigned short*)ws;                       // 8 MB
    unsigned short* Wqt  = xb  + QKV;                                 // 6 MB (3C x C)
    unsigned short* Wpt  = Wqt + (size_t)3 * C_ * C_;                 // 2 MB
    unsigned short* q    = Wpt + (size_t)C_ * C_;                     // 8 MB
    unsigned short* k    = q + QKV;
    unsigned short* v    = k + QKV;
    unsigned short* yab  = v + QKV;                                   // 8 MB
    float* cm  = (float*)(yab + QKV);
    float* qrt = cm  + (size_t)B_ * NCH * C_;
    float* ren = qrt + MT * RD;

    float* y_out   = out;
    float* idx_out = out + QKV;
    float* sc_out  = idx_out + MT * TOPB;
    float* emb_out = sc_out + MT * NCH;

    // 0) casts / transposes
    cast_bf16_kernel<<<(int)(QKV / 8 / 256), 256, 0, stream>>>(x, xb, (int)(QKV / 8));
    transpose_cast_kernel<<<dim3(3 * C_ / 64, C_ / 64), 256, 0, stream>>>(Wqkv, Wqt, C_, 3 * C_);
    transpose_cast_kernel<<<dim3(C_ / 64, C_ / 64), 256, 0, stream>>>(Wproj, Wpt, C_, C_);

    // 1) qkv projection (MFMA) -> bf16 q,k,v [B,H,T,D]
    gemm_mfma<1><<<dim3(3 * C_ / 128, MT / 128), 256, 0, stream>>>(
        xb, Wqt, bqkv, nullptr, q, k, v, (int)MT, 3 * C_, C_);

    // 2) routing path (fp32)
    chunk_mean_kernel<<<B_ * NCH, 256, 0, stream>>>(x, cm);
    rowgemm32<<<(B_ * NCH + 7) / 8, 256, 0, stream>>>(cm, Wrouter, brouter, emb_out, B_ * NCH, 0);
    l2norm_rows<<<(B_ * NCH + 7) / 8, 256, 0, stream>>>(emb_out, ren, B_ * NCH);
    rowgemm32<<<((int)MT + 7) / 8, 256, 0, stream>>>(x, Wq_rt, bq_rt, qrt, (int)MT, 1);
    scores_topk<<<((int)MT + 255) / 256, 256, 0, stream>>>(qrt, ren, sc_out, idx_out);

    // 3) MFMA flash attention -> bf16 ya [B,T,C]
    attn_mfma<<<dim3(T_ / 64, H_, B_), 256, 0, stream>>>(q, k, v, yab);

    // 4) output projection (MFMA) -> f32 y
    gemm_mfma<0><<<dim3(C_ / 128, MT / 128), 256, 0, stream>>>(
        yab, Wpt, bproj, y_out, nullptr, nullptr, nullptr, (int)MT, C_, C_);
}

// Round 4
// 267.665 us; speedup vs baseline: 8.6148x; 1.2047x over previous
//
#include <hip/hip_runtime.h>
#include <hip/hip_bf16.h>
#include <math.h>

#define B_   2
#define T_   2048
#define C_   1024
#define H_   16
#define D_   64
#define NCH  32
#define RD   32
#define TOPB 8

typedef __attribute__((ext_vector_type(8))) short bf16x8;
typedef __attribute__((ext_vector_type(4))) float f32x4;

static __device__ __forceinline__ unsigned short f2b(float f) {
    return __bfloat16_as_ushort(__float2bfloat16(f));
}

// ---------------------------------------------------------------------------
// cast x (f32) -> bf16, 8 elements per thread
// ---------------------------------------------------------------------------
__global__ __launch_bounds__(256) void cast_bf16_kernel(
    const float* __restrict__ in, unsigned short* __restrict__ out, int n8)
{
    const int i = blockIdx.x * blockDim.x + threadIdx.x;
    if (i >= n8) return;
    float4 a = ((const float4*)in)[i * 2];
    float4 b = ((const float4*)in)[i * 2 + 1];
    bf16x8 o;
    o[0] = (short)f2b(a.x); o[1] = (short)f2b(a.y);
    o[2] = (short)f2b(a.z); o[3] = (short)f2b(a.w);
    o[4] = (short)f2b(b.x); o[5] = (short)f2b(b.y);
    o[6] = (short)f2b(b.z); o[7] = (short)f2b(b.w);
    *(bf16x8*)&out[i * 8] = o;
}

// ---------------------------------------------------------------------------
// W [K][N] f32 -> Wt [N][K] bf16, 64x64 tiles via LDS
// ---------------------------------------------------------------------------
__global__ __launch_bounds__(256) void transpose_cast_kernel(
    const float* __restrict__ W, unsigned short* __restrict__ Wt, int K, int N)
{
    __shared__ float t[64][65];
    const int tid = threadIdx.x;
    const int n0 = blockIdx.x * 64, k0 = blockIdx.y * 64;
#pragma unroll
    for (int i = 0; i < 4; i++) {
        const int f = tid + i * 256;
        const int r = f >> 4, c4 = (f & 15) * 4;
        float4 v = *(const float4*)&W[(size_t)(k0 + r) * N + n0 + c4];
        t[r][c4 + 0] = v.x; t[r][c4 + 1] = v.y;
        t[r][c4 + 2] = v.z; t[r][c4 + 3] = v.w;
    }
    __syncthreads();
#pragma unroll
    for (int i = 0; i < 2; i++) {
        const int s = tid + i * 256;
        const int rn = s >> 3, ck8 = (s & 7) * 8;
        bf16x8 o;
#pragma unroll
        for (int j = 0; j < 8; j++) o[j] = (short)f2b(t[ck8 + j][rn]);
        *(bf16x8*)&Wt[(size_t)(n0 + rn) * K + k0 + ck8] = o;
    }
}

// ---------------------------------------------------------------------------
// bf16 MFMA GEMM (m97 structure): C = A[M,K] @ Bt[N,K]^T + bias
// 128x128 tile, BK=32, 256 threads = 4 waves (2x2), 64x64 per wave.
// MODE 0: f32 out[M,N].  MODE 1: qkv scatter -> bf16 [B,H,T,D].
// ---------------------------------------------------------------------------
template <int MODE>
__global__ __launch_bounds__(256) void gemm_mfma(
    const unsigned short* __restrict__ A, const unsigned short* __restrict__ Bt,
    const float* __restrict__ bias, float* __restrict__ out,
    unsigned short* __restrict__ qp, unsigned short* __restrict__ kp,
    unsigned short* __restrict__ vp, int M, int N, int K)
{
    __shared__ unsigned short As[128 * 32];
    __shared__ unsigned short Bs[128 * 32];

    const int tid  = threadIdx.x;
    const int lane = tid & 63;
    const int wave = tid >> 6;
    const int lr = lane & 15, lg = lane >> 4;
    const int wm = wave >> 1, wn = wave & 1;
    const int n0 = blockIdx.x * 128, m0 = blockIdx.y * 128;

    const int srow = tid >> 2;
    const int scol = (tid & 3) * 8;
    const unsigned short* ga = A  + (size_t)(m0 + srow) * K + scol;
    const unsigned short* gb = Bt + (size_t)(n0 + srow) * K + scol;
    const int ldst = (tid & 0xC0) * 8;

    f32x4 acc[4][4];
#pragma unroll
    for (int i = 0; i < 4; i++)
#pragma unroll
        for (int j = 0; j < 4; j++) acc[i][j] = (f32x4){0.f, 0.f, 0.f, 0.f};

    for (int k0 = 0; k0 < K; k0 += 32) {
        __syncthreads();
#pragma unroll
        for (int i = 0; i < 2; i++) {
            __builtin_amdgcn_global_load_lds(
                (const __attribute__((address_space(1))) int*)(ga + k0 + (size_t)i * 64 * K),
                (__attribute__((address_space(3))) int*)&As[i * 2048 + ldst], 16, 0, 0);
            __builtin_amdgcn_global_load_lds(
                (const __attribute__((address_space(1))) int*)(gb + k0 + (size_t)i * 64 * K),
                (__attribute__((address_space(3))) int*)&Bs[i * 2048 + ldst], 16, 0, 0);
        }
        __syncthreads();

        bf16x8 af[4], bfr[4];
#pragma unroll
        for (int mi = 0; mi < 4; mi++)
            af[mi] = *(const bf16x8*)&As[(wm * 64 + mi * 16 + lr) * 32 + lg * 8];
#pragma unroll
        for (int ni = 0; ni < 4; ni++)
            bfr[ni] = *(const bf16x8*)&Bs[(wn * 64 + ni * 16 + lr) * 32 + lg * 8];
#pragma unroll
        for (int mi = 0; mi < 4; mi++)
#pragma unroll
            for (int ni = 0; ni < 4; ni++)
                acc[mi][ni] = __builtin_amdgcn_mfma_f32_16x16x32_bf16(
                    af[mi], bfr[ni], acc[mi][ni], 0, 0, 0);
    }

#pragma unroll
    for (int ni = 0; ni < 4; ni++) {
        const int col = n0 + wn * 64 + ni * 16 + lr;
        const float bv = bias[col];
        if (MODE == 0) {
#pragma unroll
            for (int mi = 0; mi < 4; mi++) {
#pragma unroll
                for (int r = 0; r < 4; r++) {
                    const int row = m0 + wm * 64 + mi * 16 + lg * 4 + r;
                    out[(size_t)row * N + col] = acc[mi][ni][r] + bv;
                }
            }
        } else {
            const int which = col >> 10;
            const int c  = col & 1023;
            const int hh = c >> 6;
            const int dd = c & 63;
            unsigned short* dst = (which == 0) ? qp : (which == 1) ? kp : vp;
#pragma unroll
            for (int mi = 0; mi < 4; mi++) {
#pragma unroll
                for (int r = 0; r < 4; r++) {
                    const int row = m0 + wm * 64 + mi * 16 + lg * 4 + r;
                    const int bb = row >> 11, tt = row & 2047;
                    dst[(((size_t)bb * H_ + hh) * T_ + tt) * D_ + dd] =
                        f2b(acc[mi][ni][r] + bv);
                }
            }
        }
    }
}

// ---------------------------------------------------------------------------
// chunk means
// ---------------------------------------------------------------------------
__global__ void chunk_mean_kernel(const float* __restrict__ x, float* __restrict__ cm)
{
    const int bc = blockIdx.x;
    const int b = bc >> 5, n = bc & 31;
    const float* xp = x + ((size_t)b * T_ + n * 64) * C_;
    for (int c = threadIdx.x; c < C_; c += blockDim.x) {
        float s = 0.f;
        for (int i = 0; i < 64; i++) s += xp[(size_t)i * C_ + c];
        cm[(size_t)bc * C_ + c] = s * (1.0f / 64.0f);
    }
}

// ---------------------------------------------------------------------------
// rowgemm32 / l2norm
// ---------------------------------------------------------------------------
__global__ void rowgemm32(const float* __restrict__ A, const float* __restrict__ W,
                          const float* __restrict__ bias, float* __restrict__ dst,
                          int M, int normalize)
{
    const int row  = blockIdx.x * 8 + (threadIdx.x >> 5);
    const int lane = threadIdx.x & 31;
    if (row >= M) return;
    const float* a = A + (size_t)row * C_;
    float acc = 0.f;
    for (int k = 0; k < C_; k += 4) {
        float4 a4 = *(const float4*)&a[k];
        acc += a4.x * W[(k + 0) * RD + lane];
        acc += a4.y * W[(k + 1) * RD + lane];
        acc += a4.z * W[(k + 2) * RD + lane];
        acc += a4.w * W[(k + 3) * RD + lane];
    }
    acc += bias[lane];
    if (normalize) {
        float ss = acc * acc;
#pragma unroll
        for (int off = 16; off >= 1; off >>= 1) ss += __shfl_xor(ss, off, 32);
        acc = acc / fmaxf(sqrtf(ss), 1e-12f);
    }
    dst[(size_t)row * RD + lane] = acc;
}

__global__ void l2norm_rows(const float* __restrict__ src, float* __restrict__ dst, int M)
{
    const int row  = blockIdx.x * 8 + (threadIdx.x >> 5);
    const int lane = threadIdx.x & 31;
    if (row >= M) return;
    float v = src[(size_t)row * RD + lane];
    float ss = v * v;
#pragma unroll
    for (int off = 16; off >= 1; off >>= 1) ss += __shfl_xor(ss, off, 32);
    dst[(size_t)row * RD + lane] = v / fmaxf(sqrtf(ss), 1e-12f);
}

// ---------------------------------------------------------------------------
// routing scores + top-8
// ---------------------------------------------------------------------------
__global__ void scores_topk(const float* __restrict__ qrt, const float* __restrict__ ren,
                            float* __restrict__ sc_out, float* __restrict__ idx_out)
{
    const int row = blockIdx.x * blockDim.x + threadIdx.x;
    if (row >= B_ * T_) return;
    const int b = row / T_;
    float q[RD];
#pragma unroll
    for (int i = 0; i < RD; i++) q[i] = qrt[(size_t)row * RD + i];
    const float* rb = ren + (size_t)b * NCH * RD;
    float s[NCH];
#pragma unroll 4
    for (int n = 0; n < NCH; n++) {
        float acc = 0.f;
#pragma unroll
        for (int i = 0; i < RD; i++) acc += q[i] * rb[n * RD + i];
        s[n] = acc;
        sc_out[(size_t)row * NCH + n] = acc;
    }
    unsigned mask = 0;
    for (int t = 0; t < TOPB; t++) {
        float best = -INFINITY;
        int bi = 0;
#pragma unroll
        for (int n = 0; n < NCH; n++) {
            const bool ok = !((mask >> n) & 1u) && (s[n] > best);
            if (ok) { best = s[n]; bi = n; }
        }
        mask |= (1u << bi);
        idx_out[(size_t)row * TOPB + t] = (float)bi;
    }
}

// ---------------------------------------------------------------------------
// MFMA bf16 flash attention, v2.
//  - flat grid, bijective remap: long blocks (qt high) first; same-head
//    blocks pinned to one XCD (bid&7 -> h in {x, x+8}) for K/V L2 residency
//  - LDS stride 78 shorts (39 dw): fragment reads land 2 lanes/bank (free)
//  - V^T staged via paired-dword writes (2 rows packed per ds_write_b32)
//  - async-split staging: next tile's K/V global loads issued before compute
// ---------------------------------------------------------------------------
#define LSTR 78

__global__ __launch_bounds__(256) void attn_mfma(
    const unsigned short* __restrict__ qg, const unsigned short* __restrict__ kg,
    const unsigned short* __restrict__ vg, unsigned short* __restrict__ y)
{
    // bijective remap of 1024 blocks -> (qt, h, b)
    const int bid = blockIdx.x;
    const int xcd = bid & 7;
    const int j   = bid >> 3;                 // 0..127
    const int h   = xcd + 8 * (j & 1);
    const int b   = (j >> 1) & 1;
    const int qt  = 31 - (j >> 2);

    const int tid  = threadIdx.x;
    const int wave = tid >> 6;
    const int lane = tid & 63;
    const int lg = lane >> 4;
    const int lr = lane & 15;

    __shared__ short Ks[64][LSTR];
    __shared__ short Vt[64][LSTR];      // Vt[d][kv]
    __shared__ short Ps[4][16][LSTR];

    const size_t base = ((size_t)(b * H_ + h) * T_) * D_;

    // Q fragments, hoisted
    bf16x8 qf[2];
    {
        const int qrow = qt * 64 + wave * 16 + lr;
        const short* qp = (const short*)qg + base + (size_t)qrow * D_;
        qf[0] = *(const bf16x8*)&qp[lg * 8];
        qf[1] = *(const bf16x8*)&qp[32 + lg * 8];
    }

    // staging indices
    const int srr = tid >> 2;            // K row 0..63
    const int sc0 = (tid & 3) * 16;      // K col base
    const int vrp = tid >> 3;            // V row-pair 0..31
    const int vcg = tid & 7;             // V col-group 0..7

    bf16x8 kreg0, kreg1, vreg0, vreg1;

    float m_run[4], l_run[4];
    f32x4 oacc[4];
#pragma unroll
    for (int r = 0; r < 4; r++) {
        m_run[r] = -INFINITY;
        l_run[r] = 0.f;
        oacc[r] = (f32x4){0.f, 0.f, 0.f, 0.f};
    }

    const int nkt = qt + 1;

    // prologue loads for tile 0
    {
        const short* kp = (const short*)kg + base + (size_t)srr * D_ + sc0;
        kreg0 = *(const bf16x8*)kp;
        kreg1 = *(const bf16x8*)(kp + 8);
        const short* vp = (const short*)vg + base + (size_t)(2 * vrp) * D_ + vcg * 8;
        vreg0 = *(const bf16x8*)vp;
        vreg1 = *(const bf16x8*)(vp + D_);
    }

    for (int kt = 0; kt < nkt; ++kt) {
        __syncthreads();    // prior tile's LDS consumers done
        // write staged K / V^T
        *(bf16x8*)&Ks[srr][sc0]     = kreg0;
        *(bf16x8*)&Ks[srr][sc0 + 8] = kreg1;
#pragma unroll
        for (int jj = 0; jj < 8; jj++) {
            const unsigned int dw = ((unsigned int)(unsigned short)vreg0[jj]) |
                                    (((unsigned int)(unsigned short)vreg1[jj]) << 16);
            *(unsigned int*)&Vt[vcg * 8 + jj][2 * vrp] = dw;
        }
        __syncthreads();

        // issue next tile's global loads (latency hides under compute)
        if (kt + 1 < nkt) {
            const short* kp = (const short*)kg + base + (size_t)((kt + 1) * 64 + srr) * D_ + sc0;
            kreg0 = *(const bf16x8*)kp;
            kreg1 = *(const bf16x8*)(kp + 8);
            const short* vp = (const short*)vg + base + (size_t)((kt + 1) * 64 + 2 * vrp) * D_ + vcg * 8;
            vreg0 = *(const bf16x8*)vp;
            vreg1 = *(const bf16x8*)(vp + D_);
        }

        // QK^T
        f32x4 s[4];
#pragma unroll
        for (int cb = 0; cb < 4; cb++) {
            bf16x8 kf0 = *(const bf16x8*)&Ks[cb * 16 + lr][lg * 8];
            bf16x8 kf1 = *(const bf16x8*)&Ks[cb * 16 + lr][32 + lg * 8];
            f32x4 acc = (f32x4){0.f, 0.f, 0.f, 0.f};
            acc = __builtin_amdgcn_mfma_f32_16x16x32_bf16(qf[0], kf0, acc, 0, 0, 0);
            acc = __builtin_amdgcn_mfma_f32_16x16x32_bf16(qf[1], kf1, acc, 0, 0, 0);
            s[cb] = acc;
        }

        // scale + causal mask (diagonal tile only)
        const int row0 = qt * 64 + wave * 16 + lg * 4;
        if (kt == nkt - 1) {
#pragma unroll
            for (int cb = 0; cb < 4; cb++) {
                const int col_g = kt * 64 + cb * 16 + lr;
#pragma unroll
                for (int r = 0; r < 4; r++) {
                    float sv = s[cb][r] * 0.125f;
                    if (col_g > row0 + r) sv = -INFINITY;
                    s[cb][r] = sv;
                }
            }
        } else {
#pragma unroll
            for (int cb = 0; cb < 4; cb++)
#pragma unroll
                for (int r = 0; r < 4; r++) s[cb][r] *= 0.125f;
        }

        // row max over 4 col blocks + 16 lanes
        float rm[4];
#pragma unroll
        for (int r = 0; r < 4; r++)
            rm[r] = fmaxf(fmaxf(s[0][r], s[1][r]), fmaxf(s[2][r], s[3][r]));
#pragma unroll
        for (int off = 1; off <= 8; off <<= 1)
#pragma unroll
            for (int r = 0; r < 4; r++) rm[r] = fmaxf(rm[r], __shfl_xor(rm[r], off));

        float mnew[4], fsc[4];
#pragma unroll
        for (int r = 0; r < 4; r++) {
            mnew[r] = fmaxf(m_run[r], rm[r]);
            fsc[r]  = __expf(m_run[r] - mnew[r]);
            m_run[r] = mnew[r];
        }

        // P = exp(S - m) -> bf16 wave-private LDS; row sums
        float rs[4] = {0.f, 0.f, 0.f, 0.f};
#pragma unroll
        for (int cb = 0; cb < 4; cb++) {
#pragma unroll
            for (int r = 0; r < 4; r++) {
                const float p = __expf(s[cb][r] - mnew[r]);
                rs[r] += p;
                Ps[wave][lg * 4 + r][cb * 16 + lr] = (short)f2b(p);
            }
        }
#pragma unroll
        for (int off = 1; off <= 8; off <<= 1)
#pragma unroll
            for (int r = 0; r < 4; r++) rs[r] += __shfl_xor(rs[r], off);
#pragma unroll
        for (int r = 0; r < 4; r++) l_run[r] = l_run[r] * fsc[r] + rs[r];

#pragma unroll
        for (int db = 0; db < 4; db++)
#pragma unroll
            for (int r = 0; r < 4; r++) oacc[db][r] *= fsc[r];

        // PV
        bf16x8 pf0 = *(const bf16x8*)&Ps[wave][lr][lg * 8];
        bf16x8 pf1 = *(const bf16x8*)&Ps[wave][lr][32 + lg * 8];
#pragma unroll
        for (int db = 0; db < 4; db++) {
            bf16x8 vf0 = *(const bf16x8*)&Vt[db * 16 + lr][lg * 8];
            bf16x8 vf1 = *(const bf16x8*)&Vt[db * 16 + lr][32 + lg * 8];
            oacc[db] = __builtin_amdgcn_mfma_f32_16x16x32_bf16(pf0, vf0, oacc[db], 0, 0, 0);
            oacc[db] = __builtin_amdgcn_mfma_f32_16x16x32_bf16(pf1, vf1, oacc[db], 0, 0, 0);
        }
    }

#pragma unroll
    for (int r = 0; r < 4; r++) {
        const float inv = 1.0f / l_run[r];
        const int trow = qt * 64 + wave * 16 + lg * 4 + r;
        unsigned short* yp = y + (size_t)(b * T_ + trow) * C_ + h * D_;
#pragma unroll
        for (int db = 0; db < 4; db++)
            yp[db * 16 + lr] = f2b(oacc[db][r] * inv);
    }
}

// ---------------------------------------------------------------------------
extern "C" void kernel_launch(void* const* d_in, const int* in_sizes, int n_in,
                              void* d_out, int out_size, void* d_ws, size_t ws_size,
                              hipStream_t stream)
{
    const float* x       = (const float*)d_in[0];
    const float* Wqkv    = (const float*)d_in[1];
    const float* bqkv    = (const float*)d_in[2];
    const float* Wproj   = (const float*)d_in[3];
    const float* bproj   = (const float*)d_in[4];
    const float* Wrouter = (const float*)d_in[5];
    const float* brouter = (const float*)d_in[6];
    const float* Wq_rt   = (const float*)d_in[7];
    const float* bq_rt   = (const float*)d_in[8];

    float* out = (float*)d_out;
    char*  ws  = (char*)d_ws;

    const size_t MT  = (size_t)B_ * T_;          // 4096
    const size_t QKV = MT * C_;                  // 4 Mi elems

    unsigned short* xb   = (unsigned short*)ws;
    unsigned short* Wqt  = xb  + QKV;
    unsigned short* Wpt  = Wqt + (size_t)3 * C_ * C_;
    unsigned short* q    = Wpt + (size_t)C_ * C_;
    unsigned short* k    = q + QKV;
    unsigned short* v    = k + QKV;
    unsigned short* yab  = v + QKV;
    float* cm  = (float*)(yab + QKV);
    float* qrt = cm  + (size_t)B_ * NCH * C_;
    float* ren = qrt + MT * RD;

    float* y_out   = out;
    float* idx_out = out + QKV;
    float* sc_out  = idx_out + MT * TOPB;
    float* emb_out = sc_out + MT * NCH;

    // 0) casts / transposes
    cast_bf16_kernel<<<(int)(QKV / 8 / 256), 256, 0, stream>>>(x, xb, (int)(QKV / 8));
    transpose_cast_kernel<<<dim3(3 * C_ / 64, C_ / 64), 256, 0, stream>>>(Wqkv, Wqt, C_, 3 * C_);
    transpose_cast_kernel<<<dim3(C_ / 64, C_ / 64), 256, 0, stream>>>(Wproj, Wpt, C_, C_);

    // 1) qkv projection (MFMA) -> bf16 q,k,v [B,H,T,D]
    gemm_mfma<1><<<dim3(3 * C_ / 128, MT / 128), 256, 0, stream>>>(
        xb, Wqt, bqkv, nullptr, q, k, v, (int)MT, 3 * C_, C_);

    // 2) routing path (fp32)
    chunk_mean_kernel<<<B_ * NCH, 256, 0, stream>>>(x, cm);
    rowgemm32<<<(B_ * NCH + 7) / 8, 256, 0, stream>>>(cm, Wrouter, brouter, emb_out, B_ * NCH, 0);
    l2norm_rows<<<(B_ * NCH + 7) / 8, 256, 0, stream>>>(emb_out, ren, B_ * NCH);
    rowgemm32<<<((int)MT + 7) / 8, 256, 0, stream>>>(x, Wq_rt, bq_rt, qrt, (int)MT, 1);
    scores_topk<<<((int)MT + 255) / 256, 256, 0, stream>>>(qrt, ren, sc_out, idx_out);

    // 3) MFMA flash attention -> bf16 ya [B,T,C]
    attn_mfma<<<dim3(1024), 256, 0, stream>>>(q, k, v, yab);

    // 4) output projection (MFMA) -> f32 y
    gemm_mfma<0><<<dim3(C_ / 128, MT / 128), 256, 0, stream>>>(
        yab, Wpt, bproj, y_out, nullptr, nullptr, nullptr, (int)MT, C_, C_);
}